// Round 19
// baseline (467.066 us; speedup 1.0000x reference)
//
#include <hip/hip_runtime.h>
#include <hip/hip_bf16.h>
#include <stdint.h>

// BaseLayer MoE block. I/O f32, GEMMs bf16 MFMA. T=8192, D=1024, F=4096, E=8.
// R19: R17 (best, 300.6us) + ln_scores fused into the fat kernel:
//   block 0       = assignment (spin-gates on ln-completion counter)
//   blocks 1..2048 = LN+scores, 4 tokens each (4x256-thr groups)
//   blocks 2049..  = weight transpose (4096 blocks, unchanged)
// GEMM1 reverted to R17 geometry (256x128, 512thr — R18's 128^2 raised B-panel
// refetch, FETCH 81->107MB, +10us). gemm_ring/assign byte-identical to R17.

#define T_TOK 8192
#define DM    1024
#define FF    4096
#define NE    8
#define CAP   1024

typedef __attribute__((ext_vector_type(8))) __bf16 bf16x8;
typedef __attribute__((ext_vector_type(4))) float  f32x4;

__device__ __forceinline__ unsigned short f2bf(float f) {
  unsigned u = __float_as_uint(f);
  u += 0x7FFFu + ((u >> 16) & 1u);   // round-to-nearest-even
  return (unsigned short)(u >> 16);
}
__device__ __forceinline__ unsigned keyu(float s) {
  unsigned bb = __float_as_uint(s);
  return (bb & 0x80000000u) ? ~bb : (bb | 0x80000000u);  // order-preserving
}
__device__ __forceinline__ void gload_lds16(const void* g, void* l) {
  __builtin_amdgcn_global_load_lds(
      (const __attribute__((address_space(1))) unsigned int*)(uintptr_t)g,
      (__attribute__((address_space(3))) unsigned int*)l, 16, 0, 0);
}

// ---- LN + centroid scores for ONE token per 256-thread group ---------------
// 1024-thr block = 4 groups; barrier counts uniform across groups.
__device__ void ln_group(const float* __restrict__ x, const float* __restrict__ g,
                         const float* __restrict__ b, const float* __restrict__ cent,
                         unsigned short* __restrict__ nrm, float* __restrict__ scores,
                         int t, char* smem) {
  float (*red)[8]  = (float (*)[8])smem;                  // [4][8]
  float (*sred)[4] = (float (*)[4])(smem + 128);          // [4][4]
  const int tid = threadIdx.x;
  const int grp = tid >> 8, tg = tid & 255;
  const int lane = tid & 63, w = (tid >> 6) & 3;
  float4 v = ((const float4*)(x + (size_t)t * DM))[tg];
  float f0 = v.x, f1 = v.y, f2 = v.z, f3 = v.w;
  float s = f0 + f1 + f2 + f3;
  float sq = f0 * f0 + f1 * f1 + f2 * f2 + f3 * f3;
#pragma unroll
  for (int o = 32; o > 0; o >>= 1) { s += __shfl_xor(s, o); sq += __shfl_xor(sq, o); }
  __shared__ float dummy_guard;  // (unused; keeps layout explicit)
  if (lane == 0) { red[grp][w] = s; red[grp][4 + w] = sq; }
  __syncthreads();
  float S = red[grp][0] + red[grp][1] + red[grp][2] + red[grp][3];
  float SQ = red[grp][4] + red[grp][5] + red[grp][6] + red[grp][7];
  float mu = S * (1.0f / DM);
  float var = SQ * (1.0f / DM) - mu * mu;
  float rstd = rsqrtf(var + 1e-5f);
  float4 gv = ((const float4*)g)[tg];
  float4 bv = ((const float4*)b)[tg];
  float n0 = (f0 - mu) * rstd * gv.x + bv.x;
  float n1 = (f1 - mu) * rstd * gv.y + bv.y;
  float n2 = (f2 - mu) * rstd * gv.z + bv.z;
  float n3 = (f3 - mu) * rstd * gv.w + bv.w;
  ushort4 o4;
  o4.x = f2bf(n0); o4.y = f2bf(n1); o4.z = f2bf(n2); o4.w = f2bf(n3);
  ((ushort4*)(nrm + (size_t)t * DM))[tg] = o4;
  for (int e = 0; e < NE; ++e) {
    float4 cv = ((const float4*)(cent + e * DM))[tg];
    float p = n0 * cv.x + n1 * cv.y + n2 * cv.z + n3 * cv.w;
#pragma unroll
    for (int o = 32; o > 0; o >>= 1) p += __shfl_xor(p, o);
    if (lane == 0) sred[grp][w] = p;
    __syncthreads();
    if (tg == 0)
      scores[(size_t)e * T_TOK + t] =
          sred[grp][0] + sred[grp][1] + sred[grp][2] + sred[grp][3];
    __syncthreads();
  }
}

// ---- wave-0 helpers (R17-verbatim) -----------------------------------------
__device__ __forceinline__ void pivot_scan(const unsigned* hist, unsigned* S,
                                           int l) {
  unsigned v0 = hist[4 * l], v1 = hist[4 * l + 1];
  unsigned v2 = hist[4 * l + 2], v3 = hist[4 * l + 3];
  unsigned own = v0 + v1 + v2 + v3;
  unsigned s = own;
#pragma unroll
  for (int off = 1; off < 64; off <<= 1) {
    unsigned t = __shfl_down(s, off);
    if (l + off < 64) s += t;
  }
  unsigned i3 = (s - own) + v3;
  unsigned i2 = i3 + v2;
  unsigned i1 = i2 + v1;
  unsigned i0 = i1 + v0;
  unsigned need = S[0];
  if (i0 >= need && i0 - v0 < need) { S[1] = 4 * l + 0; S[0] = need - (i0 - v0); }
  if (i1 >= need && i1 - v1 < need) { S[1] = 4 * l + 1; S[0] = need - (i1 - v1); }
  if (i2 >= need && i2 - v2 < need) { S[1] = 4 * l + 2; S[0] = need - (i2 - v2); }
  if (i3 >= need && i3 - v3 < need) { S[1] = 4 * l + 3; S[0] = need - (i3 - v3); }
}
__device__ __forceinline__ void tie_select(const unsigned* bmap, unsigned* S,
                                           int* tokdst, unsigned char* taken,
                                           int l) {
  unsigned wds[4] = {bmap[4 * l], bmap[4 * l + 1], bmap[4 * l + 2], bmap[4 * l + 3]};
  unsigned cnt = __popc(wds[0]) + __popc(wds[1]) + __popc(wds[2]) + __popc(wds[3]);
  unsigned p = cnt;
#pragma unroll
  for (int off = 1; off < 64; off <<= 1) {
    unsigned t = __shfl_up(p, off);
    if (l >= off) p += t;
  }
  unsigned base = p - cnt;
  const unsigned r = S[0];
#pragma unroll
  for (int c = 0; c < 4; ++c) {
    unsigned word = wds[c];
    while (word && base < r) {
      int b = __ffs(word) - 1; word &= word - 1;
      int i = (4 * l + c) * 32 + b;
      unsigned pp = atomicAdd(&S[2], 1u);
      tokdst[pp] = i; taken[i] = 1;
      ++base;
    }
    base += __popc(word);
  }
}

// ---- assignment body v4 (R17-verbatim) -------------------------------------
__device__ void assign_body(const float* __restrict__ scores,
                            int* __restrict__ tok, char* smem) {
  unsigned*       key   = (unsigned*)smem;                   // 32 KB
  unsigned short* candA = (unsigned short*)(smem + 32768);   // 16 KB
  unsigned short* candB = (unsigned short*)(smem + 49152);   // 16 KB
  unsigned char*  taken = (unsigned char*)(smem + 65536);    //  8 KB
  unsigned*       h0    = (unsigned*)(smem + 73728);         //  1 KB
  unsigned*       h1    = (unsigned*)(smem + 74752);         //  1 KB
  unsigned*       h2    = (unsigned*)(smem + 75776);         //  1 KB
  unsigned*       h3    = (unsigned*)(smem + 76800);         //  1 KB
  unsigned*       bmap  = (unsigned*)(smem + 77824);         //  1 KB
  unsigned*       S     = (unsigned*)(smem + 78848);         // scalars
  const int tid = threadIdx.x;
  for (int i = tid; i < T_TOK; i += 1024) taken[i] = 0;
  if (tid < 256) h0[tid] = 0;
  __syncthreads();
  for (int e = 0; e < NE; ++e) {
    const float* se = scores + (size_t)e * T_TOK;
    if (tid == 0) { S[0] = CAP; S[2] = 0; S[4] = 0; }
    else if (tid >= 256 && tid < 512) h1[tid - 256] = 0;
    __syncthreads();                                          // B1
    unsigned kreg[8];
    {
      float sc[8];
      unsigned char tk[8];
#pragma unroll
      for (int j = 0; j < 8; ++j) sc[j] = se[j * 1024 + tid];
#pragma unroll
      for (int j = 0; j < 8; ++j) tk[j] = taken[j * 1024 + tid];
#pragma unroll
      for (int j = 0; j < 8; ++j) {
        unsigned k = tk[j] ? 0u : keyu(sc[j]);
        kreg[j] = k;
        key[j * 1024 + tid] = k;
        atomicAdd(&h0[k >> 24], 1u);
      }
    }
    __syncthreads();                                          // B2
    if (tid < 64) pivot_scan(h0, S, tid);
    else if (tid >= 256 && tid < 512) h2[tid - 256] = 0;
    __syncthreads();                                          // B3
    if (tid < 256) h0[tid] = 0;
    {
      const unsigned pb = S[1];
#pragma unroll
      for (int j = 0; j < 8; ++j) {
        int i = j * 1024 + tid;
        unsigned k = kreg[j];
        unsigned by = k >> 24;
        if (by > pb) {
          unsigned p = atomicAdd(&S[2], 1u);
          tok[e * CAP + p] = i; taken[i] = 1;
        } else if (by == pb) {
          unsigned q = atomicAdd(&S[4], 1u);
          candA[q] = (unsigned short)i;
          atomicAdd(&h1[(k >> 16) & 255u], 1u);
        }
      }
    }
    __syncthreads();                                          // B4
    if (tid < 64) pivot_scan(h1, S, tid);
    else if (tid == 64) S[5] = 0;
    else if (tid >= 256 && tid < 512) h3[tid - 256] = 0;
    __syncthreads();                                          // B5
    {
      const unsigned m = S[4], pb = S[1];
      for (unsigned q = tid; q < m; q += 1024) {
        unsigned i = candA[q];
        unsigned k = key[i];
        unsigned by = (k >> 16) & 255u;
        if (by > pb) {
          unsigned p = atomicAdd(&S[2], 1u);
          tok[e * CAP + p] = (int)i; taken[i] = 1;
        } else if (by == pb) {
          unsigned p = atomicAdd(&S[5], 1u);
          candB[p] = (unsigned short)i;
          atomicAdd(&h2[(k >> 8) & 255u], 1u);
        }
      }
    }
    __syncthreads();                                          // B6
    if (tid < 64) pivot_scan(h2, S, tid);
    else if (tid == 64) S[4] = 0;
    __syncthreads();                                          // B7
    {
      const unsigned m = S[5], pb = S[1];
      for (unsigned q = tid; q < m; q += 1024) {
        unsigned i = candB[q];
        unsigned k = key[i];
        unsigned by = (k >> 8) & 255u;
        if (by > pb) {
          unsigned p = atomicAdd(&S[2], 1u);
          tok[e * CAP + p] = (int)i; taken[i] = 1;
        } else if (by == pb) {
          unsigned p = atomicAdd(&S[4], 1u);
          candA[p] = (unsigned short)i;
          atomicAdd(&h3[k & 255u], 1u);
        }
      }
    }
    __syncthreads();                                          // B8
    if (tid < 64) pivot_scan(h3, S, tid);
    else if (tid >= 256 && tid < 512) bmap[tid - 256] = 0;
    __syncthreads();                                          // B9
    {
      const unsigned m = S[4], pb = S[1];
      for (unsigned q = tid; q < m; q += 1024) {
        unsigned i = candA[q];
        unsigned by = key[i] & 255u;
        if (by > pb) {
          unsigned p = atomicAdd(&S[2], 1u);
          tok[e * CAP + p] = (int)i; taken[i] = 1;
        } else if (by == pb) {
          atomicOr(&bmap[i >> 5], 1u << (i & 31));
        }
      }
    }
    __syncthreads();                                          // B10
    if (tid < 64) tie_select(bmap, S, tok + e * CAP, taken, tid);
    __syncthreads();                                          // B11
  }
}

// ---- fat kernel: assign (spin-gated) | LN blocks | transpose blocks --------
#define LN_BLOCKS 2048
__global__ __launch_bounds__(1024) void fat_all(
    const float* __restrict__ x, const float* __restrict__ ln_g,
    const float* __restrict__ ln_b, const float* __restrict__ cent,
    unsigned short* __restrict__ nrm, float* __restrict__ scores,
    int* __restrict__ tok, unsigned* __restrict__ ctr,
    const float* __restrict__ w1, const float* __restrict__ w2,
    unsigned short* __restrict__ w1T, unsigned short* __restrict__ w2T) {
  __shared__ __align__(16) char smem[79872];
  const int bid = blockIdx.x;
  if (bid == 0) {
    // wait for all LN blocks to publish scores (device-scope protocol)
    if (threadIdx.x == 0) {
      while (atomicAdd(ctr, 0u) < LN_BLOCKS) __builtin_amdgcn_s_sleep(8);
      __threadfence();
    }
    __syncthreads();
    assign_body(scores, tok, smem);
    return;
  }
  if (bid <= LN_BLOCKS) {
    const int t = (bid - 1) * 4 + (threadIdx.x >> 8);
    ln_group(x, ln_g, ln_b, cent, nrm, scores, t, smem);
    // publish: each group leader fences its own score stores, then 1 atomic
    if ((threadIdx.x & 255) == 0) __threadfence();
    __syncthreads();
    if (threadIdx.x == 0) atomicAdd(ctr, 1u);
    return;
  }
  // ---- transpose blocks (R17-verbatim, shifted index)
  const int tix = bid - 1 - LN_BLOCKS;
  const int which = tix >> 11;           // 2048 tiles each
  const int r = tix & 2047;
  const int e = r >> 8;
  const int rr = r & 255;
  int K, N, nt, kt;
  const float* s;
  unsigned short* d;
  if (which == 0) { K = DM; N = FF; nt = rr & 31; kt = rr >> 5; s = w1; d = w1T; }
  else            { K = FF; N = DM; nt = rr & 7;  kt = rr >> 3; s = w2; d = w2T; }
  s += (size_t)e * K * N;
  d += (size_t)e * N * K;
  const int q = threadIdx.x >> 8, t2 = threadIdx.x & 255;
  const int k0 = kt * 128 + (q >> 1) * 64;
  const int n0 = nt * 128 + (q & 1) * 64;
  float (*t)[65] = (float (*)[65])(smem + q * 16640);
  for (int p = t2; p < 1024; p += 256) {
    int rw = p >> 4, c4 = (p & 15) * 4;
    float4 v = *(const float4*)(s + (size_t)(k0 + rw) * N + n0 + c4);
    t[c4 + 0][rw] = v.x; t[c4 + 1][rw] = v.y;
    t[c4 + 2][rw] = v.z; t[c4 + 3][rw] = v.w;
  }
  __syncthreads();
  for (int p = t2; p < 512; p += 256) {
    int c = p >> 3, r8 = (p & 7) * 8;
    unsigned short tmp[8];
#pragma unroll
    for (int i = 0; i < 8; ++i) tmp[i] = f2bf(t[c][r8 + i]);
    *(uint4*)(d + (size_t)(n0 + c) * K + k0 + r8) = *(const uint4*)tmp;
  }
}

// ------- BK=32 3-slot-ring MFMA GEMM (R17-verbatim) -------------------------
template <int EPI, bool GATHER, int K, int N, int BM, int BN, int TPB,
          int WM, int WN>
__global__ __launch_bounds__(TPB, 2) void gemm_ring(
    const unsigned short* __restrict__ A, const unsigned short* __restrict__ Bt,
    const float* __restrict__ bias, const int* __restrict__ tok,
    const float* __restrict__ xres, void* __restrict__ Cout) {
  constexpr int NT  = K / 32;
  constexpr int RM  = BM / WM, RN = BN / WN;
  constexpr int MR  = RM / 16, NR = RN / 16;
  constexpr int ALD = (BM * 32) / (8 * TPB);
  constexpr int BLD = (BN * 32) / (8 * TPB);
  constexpr int LD  = ALD + BLD;
  constexpr int SLOT = (BM + BN) * 32;
  __shared__ __align__(16) unsigned short lds[3 * SLOT];
  __shared__ int tokl[BM];

  const int flat = blockIdx.x + gridDim.x * (blockIdx.y + gridDim.y * blockIdx.z);
  const int nwg = gridDim.x * gridDim.y * gridDim.z;
  const int nf = (flat & 7) * (nwg >> 3) + (flat >> 3);
  const int bx = nf % gridDim.x;
  const int rem = nf / gridDim.x;
  const int e  = rem / gridDim.y;
  const int n0 = bx * BN, m0 = (rem % gridDim.y) * BM;

  const int tid = threadIdx.x, lane = tid & 63, w = tid >> 6;
  const int wr = w / WN, wc = w % WN;
  const int lr = lane & 15, lk = lane >> 4;

  for (int i = tid; i < BM; i += TPB) tokl[i] = tok[e * CAP + m0 + i];
  __syncthreads();

  const unsigned short* aptr[ALD];
  const unsigned short* bptr[BLD];
  const unsigned short* Be = Bt + (size_t)e * N * K + (size_t)n0 * K;
#pragma unroll
  for (int i = 0; i < ALD; ++i) {
    int c = i * TPB + tid, row = c >> 2, sp = c & 3;
    int s = sp ^ ((row >> 1) & 3);
    size_t grow = GATHER ? (size_t)tokl[row] : (size_t)(e * CAP + m0 + row);
    aptr[i] = A + grow * K + s * 8;
  }
#pragma unroll
  for (int i = 0; i < BLD; ++i) {
    int c = i * TPB + tid, row = c >> 2, sp = c & 3;
    int s = sp ^ ((row >> 1) & 3);
    bptr[i] = Be + (size_t)row * K + s * 8;
  }
  auto stage = [&](int tile, int slot) {
    unsigned short* base = lds + (size_t)slot * SLOT;
#pragma unroll
    for (int i = 0; i < ALD; ++i)
      gload_lds16(aptr[i] + tile * 32, base + (i * TPB + tid) * 8);
#pragma unroll
    for (int i = 0; i < BLD; ++i)
      gload_lds16(bptr[i] + tile * 32, base + BM * 32 + (i * TPB + tid) * 8);
  };

  const int swz = (lr >> 1) & 3;
  const int afo = (wr * RM + lr) * 32 + (lk ^ swz) * 8;
  const int bfo = BM * 32 + (wc * RN + lr) * 32 + (lk ^ swz) * 8;

  f32x4 acc[MR][NR] = {};

  stage(0, 0); stage(1, 1);
  asm volatile("s_waitcnt vmcnt(%0)" :: "i"(LD) : "memory");
  __builtin_amdgcn_s_barrier();

  int slot = 0;
#pragma unroll 1
  for (int t = 0; t < NT; ++t) {
    const unsigned short* base = lds + (size_t)slot * SLOT;
    bf16x8 af[MR], bfr[NR];
#pragma unroll
    for (int mi = 0; mi < MR; ++mi)
      af[mi] = *(const bf16x8*)(base + afo + mi * 512);
#pragma unroll
    for (int ni = 0; ni < NR; ++ni)
      bfr[ni] = *(const bf16x8*)(base + bfo + ni * 512);
    if (t + 2 < NT) {
      int dst = slot - 1;                   // (t+2)%3 == (t-1)%3
      if (dst < 0) dst = 2;
      stage(t + 2, dst);
      asm volatile("s_waitcnt vmcnt(%0)" :: "i"(LD) : "memory");
    } else if (t + 2 == NT) {
      asm volatile("s_waitcnt vmcnt(0)" ::: "memory");   // peel: fence t+1
    }
    __builtin_amdgcn_s_barrier();
    asm volatile("s_waitcnt lgkmcnt(0)" ::: "memory");
    __builtin_amdgcn_sched_barrier(0);
    __builtin_amdgcn_s_setprio(1);
#pragma unroll
    for (int mi = 0; mi < MR; ++mi)
#pragma unroll
      for (int ni = 0; ni < NR; ++ni)
        acc[mi][ni] = __builtin_amdgcn_mfma_f32_16x16x32_bf16(
            af[mi], bfr[ni], acc[mi][ni], 0, 0, 0);
    __builtin_amdgcn_s_setprio(0);
    __builtin_amdgcn_s_barrier();
    slot = (slot == 2) ? 0 : slot + 1;
  }

  const int lg = lane >> 4;
#pragma unroll
  for (int ni = 0; ni < NR; ++ni) {
    const int n = n0 + wc * RN + ni * 16 + lr;
    const float bb = bias[e * N + n];
#pragma unroll
    for (int mi = 0; mi < MR; ++mi) {
#pragma unroll
      for (int r = 0; r < 4; ++r) {
        const int ml = wr * RM + mi * 16 + lg * 4 + r;
        float v = acc[mi][ni][r] + bb;
        if (EPI == 1) {
          float z = 1.5957691216f * v + 0.07135481283f * v * v * v;
          float gl = v / (1.0f + __expf(-z));
          ((unsigned short*)Cout)[(size_t)(e * CAP + m0 + ml) * N + n] = f2bf(gl);
        } else {
          const int token = tokl[ml];
          v += xres[(size_t)token * DM + n];
          ((float*)Cout)[(size_t)token * (size_t)N + n] = v;
        }
      }
    }
  }
}

// ---------------- launch ----------------------------------------------------
extern "C" void kernel_launch(void* const* d_in, const int* in_sizes, int n_in,
                              void* d_out, int out_size, void* d_ws, size_t ws_size,
                              hipStream_t stream) {
  const float* x    = (const float*)d_in[0];
  const float* cent = (const float*)d_in[1];
  const float* ln_g = (const float*)d_in[2];
  const float* ln_b = (const float*)d_in[3];
  const float* w1   = (const float*)d_in[4];
  const float* b1   = (const float*)d_in[5];
  const float* w2   = (const float*)d_in[6];
  const float* b2   = (const float*)d_in[7];
  float* out = (float*)d_out;

  char* ws = (char*)d_ws;
  size_t off = 0;
  unsigned short* w1T = (unsigned short*)(ws + off); off += (size_t)NE * FF * DM * 2;
  unsigned short* w2T = (unsigned short*)(ws + off); off += (size_t)NE * DM * FF * 2;
  unsigned short* nrm = (unsigned short*)(ws + off); off += (size_t)T_TOK * DM * 2;
  unsigned short* h1  = (unsigned short*)(ws + off); off += (size_t)T_TOK * FF * 2;
  float* scores       = (float*)(ws + off);          off += (size_t)NE * T_TOK * 4;
  int* tok            = (int*)(ws + off);            off += (size_t)T_TOK * 4;
  unsigned* ctr       = (unsigned*)(ws + off);       off += 64;

  hipMemsetAsync(ctr, 0, 4, stream);
  // fat: 1 assign + 2048 LN (first, so they dispatch early) + 4096 transpose
  fat_all<<<dim3(1 + LN_BLOCKS + 4096), 1024, 0, stream>>>(
      x, ln_g, ln_b, cent, nrm, scores, tok, ctr, w1, w2, w1T, w2T);
  gemm_ring<1, true, DM, FF, 256, 128, 512, 4, 2>
      <<<dim3(FF / 128, CAP / 256, NE), 512, 0, stream>>>(nrm, w1T, b1, tok, nullptr, h1);
  gemm_ring<2, false, FF, DM, 128, 128, 256, 2, 2>
      <<<dim3(DM / 128, CAP / 128, NE), 256, 0, stream>>>(h1, w2T, b2, tok, x, out);
}

// Round 20
// 300.159 us; speedup vs baseline: 1.5561x; 1.5561x over previous
//
#include <hip/hip_runtime.h>
#include <hip/hip_bf16.h>
#include <stdint.h>

// BaseLayer MoE block. I/O f32, GEMMs bf16 MFMA. T=8192, D=1024, F=4096, E=8.
// R20 = R17 verbatim (measured best, 300.6us). R18 (GEMM1 128^2 geometry) and
// R19 (spin-gated LN fusion) both regressed; this restores the proven config:
//   ln_scores (separate) -> fat(assign || transpose) -> gemm1(256x128 ring,
//   gather+gelu) -> gemm2(128x128 ring, bias+residual+scatter).

#define T_TOK 8192
#define DM    1024
#define FF    4096
#define NE    8
#define CAP   1024

typedef __attribute__((ext_vector_type(8))) __bf16 bf16x8;
typedef __attribute__((ext_vector_type(4))) float  f32x4;

__device__ __forceinline__ unsigned short f2bf(float f) {
  unsigned u = __float_as_uint(f);
  u += 0x7FFFu + ((u >> 16) & 1u);   // round-to-nearest-even
  return (unsigned short)(u >> 16);
}
__device__ __forceinline__ unsigned keyu(float s) {
  unsigned bb = __float_as_uint(s);
  return (bb & 0x80000000u) ? ~bb : (bb | 0x80000000u);  // order-preserving
}
__device__ __forceinline__ void gload_lds16(const void* g, void* l) {
  __builtin_amdgcn_global_load_lds(
      (const __attribute__((address_space(1))) unsigned int*)(uintptr_t)g,
      (__attribute__((address_space(3))) unsigned int*)l, 16, 0, 0);
}

// ---------------- LN + centroid scores (scores stored [E][T]) ---------------
__global__ __launch_bounds__(256) void ln_scores_k(
    const float* __restrict__ x, const float* __restrict__ g,
    const float* __restrict__ b, const float* __restrict__ cent,
    unsigned short* __restrict__ nrm, float* __restrict__ scores) {
  const int t = blockIdx.x, tid = threadIdx.x;
  const int lane = tid & 63, w = tid >> 6;
  float4 v = ((const float4*)(x + (size_t)t * DM))[tid];
  float f0 = v.x, f1 = v.y, f2 = v.z, f3 = v.w;
  float s = f0 + f1 + f2 + f3;
  float sq = f0 * f0 + f1 * f1 + f2 * f2 + f3 * f3;
#pragma unroll
  for (int o = 32; o > 0; o >>= 1) { s += __shfl_xor(s, o); sq += __shfl_xor(sq, o); }
  __shared__ float red[8];
  if (lane == 0) { red[w] = s; red[4 + w] = sq; }
  __syncthreads();
  float S = red[0] + red[1] + red[2] + red[3];
  float SQ = red[4] + red[5] + red[6] + red[7];
  float mu = S * (1.0f / DM);
  float var = SQ * (1.0f / DM) - mu * mu;
  float rstd = rsqrtf(var + 1e-5f);
  float4 gv = ((const float4*)g)[tid];
  float4 bv = ((const float4*)b)[tid];
  float n0 = (f0 - mu) * rstd * gv.x + bv.x;
  float n1 = (f1 - mu) * rstd * gv.y + bv.y;
  float n2 = (f2 - mu) * rstd * gv.z + bv.z;
  float n3 = (f3 - mu) * rstd * gv.w + bv.w;
  ushort4 o4;
  o4.x = f2bf(n0); o4.y = f2bf(n1); o4.z = f2bf(n2); o4.w = f2bf(n3);
  ((ushort4*)(nrm + (size_t)t * DM))[tid] = o4;
  __shared__ float sred[4];
  for (int e = 0; e < NE; ++e) {
    float4 cv = ((const float4*)(cent + e * DM))[tid];
    float p = n0 * cv.x + n1 * cv.y + n2 * cv.z + n3 * cv.w;
#pragma unroll
    for (int o = 32; o > 0; o >>= 1) p += __shfl_xor(p, o);
    if (lane == 0) sred[w] = p;
    __syncthreads();
    if (tid == 0) scores[(size_t)e * T_TOK + t] = sred[0] + sred[1] + sred[2] + sred[3];
    __syncthreads();
  }
}

// ---- wave-0 helpers --------------------------------------------------------
__device__ __forceinline__ void pivot_scan(const unsigned* hist, unsigned* S,
                                           int l) {
  unsigned v0 = hist[4 * l], v1 = hist[4 * l + 1];
  unsigned v2 = hist[4 * l + 2], v3 = hist[4 * l + 3];
  unsigned own = v0 + v1 + v2 + v3;
  unsigned s = own;
#pragma unroll
  for (int off = 1; off < 64; off <<= 1) {
    unsigned t = __shfl_down(s, off);
    if (l + off < 64) s += t;
  }
  unsigned i3 = (s - own) + v3;
  unsigned i2 = i3 + v2;
  unsigned i1 = i2 + v1;
  unsigned i0 = i1 + v0;
  unsigned need = S[0];
  if (i0 >= need && i0 - v0 < need) { S[1] = 4 * l + 0; S[0] = need - (i0 - v0); }
  if (i1 >= need && i1 - v1 < need) { S[1] = 4 * l + 1; S[0] = need - (i1 - v1); }
  if (i2 >= need && i2 - v2 < need) { S[1] = 4 * l + 2; S[0] = need - (i2 - v2); }
  if (i3 >= need && i3 - v3 < need) { S[1] = 4 * l + 3; S[0] = need - (i3 - v3); }
}
__device__ __forceinline__ void tie_select(const unsigned* bmap, unsigned* S,
                                           int* tokdst, unsigned char* taken,
                                           int l) {
  unsigned wds[4] = {bmap[4 * l], bmap[4 * l + 1], bmap[4 * l + 2], bmap[4 * l + 3]};
  unsigned cnt = __popc(wds[0]) + __popc(wds[1]) + __popc(wds[2]) + __popc(wds[3]);
  unsigned p = cnt;
#pragma unroll
  for (int off = 1; off < 64; off <<= 1) {
    unsigned t = __shfl_up(p, off);
    if (l >= off) p += t;
  }
  unsigned base = p - cnt;
  const unsigned r = S[0];
#pragma unroll
  for (int c = 0; c < 4; ++c) {
    unsigned word = wds[c];
    while (word && base < r) {
      int b = __ffs(word) - 1; word &= word - 1;
      int i = (4 * l + c) * 32 + b;
      unsigned pp = atomicAdd(&S[2], 1u);
      tokdst[pp] = i; taken[i] = 1;
      ++base;
    }
    base += __popc(word);
  }
}

// ---- assignment body v4: fused-phase + hoisted loads + register keys -------
__device__ void assign_body(const float* __restrict__ scores,
                            int* __restrict__ tok, char* smem) {
  unsigned*       key   = (unsigned*)smem;                   // 32 KB
  unsigned short* candA = (unsigned short*)(smem + 32768);   // 16 KB
  unsigned short* candB = (unsigned short*)(smem + 49152);   // 16 KB
  unsigned char*  taken = (unsigned char*)(smem + 65536);    //  8 KB
  unsigned*       h0    = (unsigned*)(smem + 73728);         //  1 KB
  unsigned*       h1    = (unsigned*)(smem + 74752);         //  1 KB
  unsigned*       h2    = (unsigned*)(smem + 75776);         //  1 KB
  unsigned*       h3    = (unsigned*)(smem + 76800);         //  1 KB
  unsigned*       bmap  = (unsigned*)(smem + 77824);         //  1 KB
  unsigned*       S     = (unsigned*)(smem + 78848);         // scalars
  const int tid = threadIdx.x;
  for (int i = tid; i < T_TOK; i += 1024) taken[i] = 0;
  if (tid < 256) h0[tid] = 0;
  __syncthreads();
  for (int e = 0; e < NE; ++e) {
    const float* se = scores + (size_t)e * T_TOK;
    if (tid == 0) { S[0] = CAP; S[2] = 0; S[4] = 0; }
    else if (tid >= 256 && tid < 512) h1[tid - 256] = 0;
    __syncthreads();                                          // B1
    // P0: hoisted unconditional loads -> keys (regs + LDS) + level-0 hist
    unsigned kreg[8];
    {
      float sc[8];
      unsigned char tk[8];
#pragma unroll
      for (int j = 0; j < 8; ++j) sc[j] = se[j * 1024 + tid];   // 8 indep loads
#pragma unroll
      for (int j = 0; j < 8; ++j) tk[j] = taken[j * 1024 + tid];
#pragma unroll
      for (int j = 0; j < 8; ++j) {
        unsigned k = tk[j] ? 0u : keyu(sc[j]);
        kreg[j] = k;
        key[j * 1024 + tid] = k;
        atomicAdd(&h0[k >> 24], 1u);
      }
    }
    __syncthreads();                                          // B2
    // P1: pivot level 0; idle waves pre-zero h2 ONLY (h0 live here)
    if (tid < 64) pivot_scan(h0, S, tid);
    else if (tid >= 256 && tid < 512) h2[tid - 256] = 0;
    __syncthreads();                                          // B3
    // P2: zero h0 (dead) + level-0 emit from REGISTER keys + fused h1
    if (tid < 256) h0[tid] = 0;
    {
      const unsigned pb = S[1];
#pragma unroll
      for (int j = 0; j < 8; ++j) {
        int i = j * 1024 + tid;
        unsigned k = kreg[j];
        unsigned by = k >> 24;
        if (by > pb) {
          unsigned p = atomicAdd(&S[2], 1u);
          tok[e * CAP + p] = i; taken[i] = 1;
        } else if (by == pb) {
          unsigned q = atomicAdd(&S[4], 1u);
          candA[q] = (unsigned short)i;
          atomicAdd(&h1[(k >> 16) & 255u], 1u);
        }
      }
    }
    __syncthreads();                                          // B4
    // P3: pivot level 1; zero h3; reset candB counter
    if (tid < 64) pivot_scan(h1, S, tid);
    else if (tid == 64) S[5] = 0;
    else if (tid >= 256 && tid < 512) h3[tid - 256] = 0;
    __syncthreads();                                          // B5
    // P4: level-1 emit candA -> candB + fused level-2 histogram
    {
      const unsigned m = S[4], pb = S[1];
      for (unsigned q = tid; q < m; q += 1024) {
        unsigned i = candA[q];
        unsigned k = key[i];
        unsigned by = (k >> 16) & 255u;
        if (by > pb) {
          unsigned p = atomicAdd(&S[2], 1u);
          tok[e * CAP + p] = (int)i; taken[i] = 1;
        } else if (by == pb) {
          unsigned p = atomicAdd(&S[5], 1u);
          candB[p] = (unsigned short)i;
          atomicAdd(&h2[(k >> 8) & 255u], 1u);
        }
      }
    }
    __syncthreads();                                          // B6
    // P5: pivot level 2; reset candA counter
    if (tid < 64) pivot_scan(h2, S, tid);
    else if (tid == 64) S[4] = 0;
    __syncthreads();                                          // B7
    // P6: level-2 emit candB -> candA + fused level-3 histogram
    {
      const unsigned m = S[5], pb = S[1];
      for (unsigned q = tid; q < m; q += 1024) {
        unsigned i = candB[q];
        unsigned k = key[i];
        unsigned by = (k >> 8) & 255u;
        if (by > pb) {
          unsigned p = atomicAdd(&S[2], 1u);
          tok[e * CAP + p] = (int)i; taken[i] = 1;
        } else if (by == pb) {
          unsigned p = atomicAdd(&S[4], 1u);
          candA[p] = (unsigned short)i;
          atomicAdd(&h3[k & 255u], 1u);
        }
      }
    }
    __syncthreads();                                          // B8
    // P7: pivot level 3; zero bitmap
    if (tid < 64) pivot_scan(h3, S, tid);
    else if (tid >= 256 && tid < 512) bmap[tid - 256] = 0;
    __syncthreads();                                          // B9
    // P8: level-3 emit candA; exact-pivot -> bitmap
    {
      const unsigned m = S[4], pb = S[1];
      for (unsigned q = tid; q < m; q += 1024) {
        unsigned i = candA[q];
        unsigned by = key[i] & 255u;
        if (by > pb) {
          unsigned p = atomicAdd(&S[2], 1u);
          tok[e * CAP + p] = (int)i; taken[i] = 1;
        } else if (by == pb) {
          atomicOr(&bmap[i >> 5], 1u << (i & 31));
        }
      }
    }
    __syncthreads();                                          // B10
    // P9: ties - S[0] lowest-index pivot-ties win
    if (tid < 64) tie_select(bmap, S, tok + e * CAP, taken, tid);
    __syncthreads();                                          // B11
  }
}

// ---- fat kernel: block 0 = assignment; blocks 1.. = weight transpose -------
__global__ __launch_bounds__(1024) void fat_assign_transpose(
    const float* __restrict__ scores, int* __restrict__ tok,
    const float* __restrict__ w1, const float* __restrict__ w2,
    unsigned short* __restrict__ w1T, unsigned short* __restrict__ w2T) {
  __shared__ __align__(16) char smem[79872];
  if (blockIdx.x == 0) { assign_body(scores, tok, smem); return; }
  const int tix = blockIdx.x - 1;
  const int which = tix >> 11;           // 2048 tiles each
  const int r = tix & 2047;
  const int e = r >> 8;
  const int rr = r & 255;
  int K, N, nt, kt;
  const float* s;
  unsigned short* d;
  if (which == 0) { K = DM; N = FF; nt = rr & 31; kt = rr >> 5; s = w1; d = w1T; }
  else            { K = FF; N = DM; nt = rr & 7;  kt = rr >> 3; s = w2; d = w2T; }
  s += (size_t)e * K * N;
  d += (size_t)e * N * K;
  const int q = threadIdx.x >> 8, t2 = threadIdx.x & 255;
  const int k0 = kt * 128 + (q >> 1) * 64;
  const int n0 = nt * 128 + (q & 1) * 64;
  float (*t)[65] = (float (*)[65])(smem + q * 16640);
  for (int p = t2; p < 1024; p += 256) {
    int rw = p >> 4, c4 = (p & 15) * 4;
    float4 v = *(const float4*)(s + (size_t)(k0 + rw) * N + n0 + c4);
    t[c4 + 0][rw] = v.x; t[c4 + 1][rw] = v.y;
    t[c4 + 2][rw] = v.z; t[c4 + 3][rw] = v.w;
  }
  __syncthreads();
  for (int p = t2; p < 512; p += 256) {
    int c = p >> 3, r8 = (p & 7) * 8;
    unsigned short tmp[8];
#pragma unroll
    for (int i = 0; i < 8; ++i) tmp[i] = f2bf(t[c][r8 + i]);
    *(uint4*)(d + (size_t)(n0 + c) * K + k0 + r8) = *(const uint4*)tmp;
  }
}

// ------- BK=32 3-slot-ring MFMA GEMM (unchanged from R11) -------------------
template <int EPI, bool GATHER, int K, int N, int BM, int BN, int TPB,
          int WM, int WN>
__global__ __launch_bounds__(TPB, 2) void gemm_ring(
    const unsigned short* __restrict__ A, const unsigned short* __restrict__ Bt,
    const float* __restrict__ bias, const int* __restrict__ tok,
    const float* __restrict__ xres, void* __restrict__ Cout) {
  constexpr int NT  = K / 32;
  constexpr int RM  = BM / WM, RN = BN / WN;
  constexpr int MR  = RM / 16, NR = RN / 16;
  constexpr int ALD = (BM * 32) / (8 * TPB);
  constexpr int BLD = (BN * 32) / (8 * TPB);
  constexpr int LD  = ALD + BLD;
  constexpr int SLOT = (BM + BN) * 32;
  __shared__ __align__(16) unsigned short lds[3 * SLOT];
  __shared__ int tokl[BM];

  const int flat = blockIdx.x + gridDim.x * (blockIdx.y + gridDim.y * blockIdx.z);
  const int nwg = gridDim.x * gridDim.y * gridDim.z;
  const int nf = (flat & 7) * (nwg >> 3) + (flat >> 3);
  const int bx = nf % gridDim.x;
  const int rem = nf / gridDim.x;
  const int e  = rem / gridDim.y;
  const int n0 = bx * BN, m0 = (rem % gridDim.y) * BM;

  const int tid = threadIdx.x, lane = tid & 63, w = tid >> 6;
  const int wr = w / WN, wc = w % WN;
  const int lr = lane & 15, lk = lane >> 4;

  for (int i = tid; i < BM; i += TPB) tokl[i] = tok[e * CAP + m0 + i];
  __syncthreads();

  const unsigned short* aptr[ALD];
  const unsigned short* bptr[BLD];
  const unsigned short* Be = Bt + (size_t)e * N * K + (size_t)n0 * K;
#pragma unroll
  for (int i = 0; i < ALD; ++i) {
    int c = i * TPB + tid, row = c >> 2, sp = c & 3;
    int s = sp ^ ((row >> 1) & 3);
    size_t grow = GATHER ? (size_t)tokl[row] : (size_t)(e * CAP + m0 + row);
    aptr[i] = A + grow * K + s * 8;
  }
#pragma unroll
  for (int i = 0; i < BLD; ++i) {
    int c = i * TPB + tid, row = c >> 2, sp = c & 3;
    int s = sp ^ ((row >> 1) & 3);
    bptr[i] = Be + (size_t)row * K + s * 8;
  }
  auto stage = [&](int tile, int slot) {
    unsigned short* base = lds + (size_t)slot * SLOT;
#pragma unroll
    for (int i = 0; i < ALD; ++i)
      gload_lds16(aptr[i] + tile * 32, base + (i * TPB + tid) * 8);
#pragma unroll
    for (int i = 0; i < BLD; ++i)
      gload_lds16(bptr[i] + tile * 32, base + BM * 32 + (i * TPB + tid) * 8);
  };

  const int swz = (lr >> 1) & 3;
  const int afo = (wr * RM + lr) * 32 + (lk ^ swz) * 8;
  const int bfo = BM * 32 + (wc * RN + lr) * 32 + (lk ^ swz) * 8;

  f32x4 acc[MR][NR] = {};

  stage(0, 0); stage(1, 1);
  asm volatile("s_waitcnt vmcnt(%0)" :: "i"(LD) : "memory");
  __builtin_amdgcn_s_barrier();

  int slot = 0;
#pragma unroll 1
  for (int t = 0; t < NT; ++t) {
    const unsigned short* base = lds + (size_t)slot * SLOT;
    bf16x8 af[MR], bfr[NR];
#pragma unroll
    for (int mi = 0; mi < MR; ++mi)
      af[mi] = *(const bf16x8*)(base + afo + mi * 512);
#pragma unroll
    for (int ni = 0; ni < NR; ++ni)
      bfr[ni] = *(const bf16x8*)(base + bfo + ni * 512);
    if (t + 2 < NT) {
      int dst = slot - 1;                   // (t+2)%3 == (t-1)%3
      if (dst < 0) dst = 2;
      stage(t + 2, dst);
      asm volatile("s_waitcnt vmcnt(%0)" :: "i"(LD) : "memory");
    } else if (t + 2 == NT) {
      asm volatile("s_waitcnt vmcnt(0)" ::: "memory");   // peel: fence t+1
    }
    __builtin_amdgcn_s_barrier();
    asm volatile("s_waitcnt lgkmcnt(0)" ::: "memory");
    __builtin_amdgcn_sched_barrier(0);
    __builtin_amdgcn_s_setprio(1);
#pragma unroll
    for (int mi = 0; mi < MR; ++mi)
#pragma unroll
      for (int ni = 0; ni < NR; ++ni)
        acc[mi][ni] = __builtin_amdgcn_mfma_f32_16x16x32_bf16(
            af[mi], bfr[ni], acc[mi][ni], 0, 0, 0);
    __builtin_amdgcn_s_setprio(0);
    __builtin_amdgcn_s_barrier();
    slot = (slot == 2) ? 0 : slot + 1;
  }

  const int lg = lane >> 4;
#pragma unroll
  for (int ni = 0; ni < NR; ++ni) {
    const int n = n0 + wc * RN + ni * 16 + lr;
    const float bb = bias[e * N + n];
#pragma unroll
    for (int mi = 0; mi < MR; ++mi) {
#pragma unroll
      for (int r = 0; r < 4; ++r) {
        const int ml = wr * RM + mi * 16 + lg * 4 + r;
        float v = acc[mi][ni][r] + bb;
        if (EPI == 1) {
          float z = 1.5957691216f * v + 0.07135481283f * v * v * v;
          float gl = v / (1.0f + __expf(-z));
          ((unsigned short*)Cout)[(size_t)(e * CAP + m0 + ml) * N + n] = f2bf(gl);
        } else {
          const int token = tokl[ml];
          v += xres[(size_t)token * DM + n];
          ((float*)Cout)[(size_t)token * (size_t)N + n] = v;
        }
      }
    }
  }
}

// ---------------- launch ----------------------------------------------------
extern "C" void kernel_launch(void* const* d_in, const int* in_sizes, int n_in,
                              void* d_out, int out_size, void* d_ws, size_t ws_size,
                              hipStream_t stream) {
  const float* x    = (const float*)d_in[0];
  const float* cent = (const float*)d_in[1];
  const float* ln_g = (const float*)d_in[2];
  const float* ln_b = (const float*)d_in[3];
  const float* w1   = (const float*)d_in[4];
  const float* b1   = (const float*)d_in[5];
  const float* w2   = (const float*)d_in[6];
  const float* b2   = (const float*)d_in[7];
  float* out = (float*)d_out;

  char* ws = (char*)d_ws;
  size_t off = 0;
  unsigned short* w1T = (unsigned short*)(ws + off); off += (size_t)NE * FF * DM * 2;
  unsigned short* w2T = (unsigned short*)(ws + off); off += (size_t)NE * DM * FF * 2;
  unsigned short* nrm = (unsigned short*)(ws + off); off += (size_t)T_TOK * DM * 2;
  unsigned short* h1  = (unsigned short*)(ws + off); off += (size_t)T_TOK * FF * 2;
  float* scores       = (float*)(ws + off);          off += (size_t)NE * T_TOK * 4;
  int* tok            = (int*)(ws + off);            off += (size_t)T_TOK * 4;

  ln_scores_k<<<dim3(T_TOK), 256, 0, stream>>>(x, ln_g, ln_b, cent, nrm, scores);
  fat_assign_transpose<<<dim3(1 + 4096), 1024, 0, stream>>>(
      scores, tok, w1, w2, w1T, w2T);
  gemm_ring<1, true, DM, FF, 256, 128, 512, 4, 2>
      <<<dim3(FF / 128, CAP / 256, NE), 512, 0, stream>>>(nrm, w1T, b1, tok, nullptr, h1);
  gemm_ring<2, false, FF, DM, 128, 128, 256, 2, 2>
      <<<dim3(DM / 128, CAP / 128, NE), 256, 0, stream>>>(h1, w2T, b2, tok, x, out);
}